// Round 1
// baseline (920.334 us; speedup 1.0000x reference)
//
#include <hip/hip_runtime.h>
#include <stdint.h>

// Problem constants
#define GM 8192      // rows of x (4*2048)
#define GN 4096      // output dim (D2)
#define GK 4096      // inner dim (D1)
#define NFREQ 100
#define ALPHA_F 300.0f

typedef __bf16 bf16;
typedef __attribute__((ext_vector_type(8))) __bf16 bf16x8;
typedef __attribute__((ext_vector_type(4))) float f32x4;

__device__ __forceinline__ bf16 f2bf(float f) {
  union { float f; uint32_t u; } v; v.f = f;
  uint32_t r = v.u + 0x7FFFu + ((v.u >> 16) & 1u);   // RNE, no NaN handling needed
  uint16_t h = (uint16_t)(r >> 16);
  return __builtin_bit_cast(bf16, h);
}

// ---------------- K1: build rank-200 factor tables ----------------
// Delta_W[k,l] = s * sum_j c_j cos(2π(k*r_j + l*q_j)/4096),  s = ALPHA/(D1*D2)
// Delta_W^T = P @ Q  with:
//   Q[j][k]      = s*c_j*cos(2π k r_j/4096)   Q[N+j][k] = s*c_j*sin(...)
//   P[l][j]      = cos(2π l q_j/4096)          P[l][N+j] = -sin(...)
__global__ __launch_bounds__(256) void build_tables(
    const float* __restrict__ c, const long long* __restrict__ E,
    float* __restrict__ Q, float* __restrict__ P)
{
  const int j  = blockIdx.x;
  const int r  = (int)E[j];          // row freq (pairs with k)
  const int q  = (int)E[NFREQ + j];  // col freq (pairs with l)
  const float cs = c[j] * (ALPHA_F / ((float)GK * (float)GN));
  const float w = 6.28318530717958647692f / 4096.0f;
  for (int m = threadIdx.x; m < 4096; m += blockDim.x) {
    float s1, c1, s2, c2;
    sincosf(w * (float)((m * r) & 4095), &s1, &c1);   // integer phase reduction!
    Q[j * 4096 + m]           = cs * c1;
    Q[(NFREQ + j) * 4096 + m] = cs * s1;
    sincosf(w * (float)((m * q) & 4095), &s2, &c2);
    P[m * (2 * NFREQ) + j]         = c2;
    P[m * (2 * NFREQ) + NFREQ + j] = -s2;
  }
}

// ---------------- K2: cast x (f32) -> bf16, 8 elems/thread ----------------
__global__ __launch_bounds__(256) void cvt_f32_bf16(
    const float* __restrict__ in, bf16* __restrict__ out)
{
  const int i = blockIdx.x * 256 + threadIdx.x;   // i < GM*GK/8
  float4 a = ((const float4*)in)[2 * i];
  float4 b = ((const float4*)in)[2 * i + 1];
  bf16x8 o;
  o[0] = f2bf(a.x); o[1] = f2bf(a.y); o[2] = f2bf(a.z); o[3] = f2bf(a.w);
  o[4] = f2bf(b.x); o[5] = f2bf(b.y); o[6] = f2bf(b.z); o[7] = f2bf(b.w);
  ((bf16x8*)out)[i] = o;
}

// ---------------- K3: Mt[l][k] = bf16( W[l][k] + (P@Q)[l][k] ) ----------------
// block: 256 threads over 256 k's, 16 l's each; P rows staged in LDS (broadcast reads)
#define LPER 16
__global__ __launch_bounds__(256) void build_Mt(
    const float* __restrict__ W, const float* __restrict__ P,
    const float* __restrict__ Q, bf16* __restrict__ Mt)
{
  __shared__ float Pl[LPER][2 * NFREQ];
  const int l0 = blockIdx.y * LPER;
  const int k  = blockIdx.x * 256 + threadIdx.x;
  for (int idx = threadIdx.x; idx < LPER * 2 * NFREQ; idx += 256)
    Pl[idx / (2 * NFREQ)][idx % (2 * NFREQ)] =
        P[(size_t)(l0 + idx / (2 * NFREQ)) * (2 * NFREQ) + idx % (2 * NFREQ)];
  __syncthreads();

  float acc[LPER] = {};
  for (int jj = 0; jj < 2 * NFREQ; ++jj) {
    float qv = Q[jj * 4096 + k];
#pragma unroll
    for (int li = 0; li < LPER; ++li)
      acc[li] = fmaf(qv, Pl[li][jj], acc[li]);
  }
#pragma unroll
  for (int li = 0; li < LPER; ++li) {
    const int l = l0 + li;
    Mt[(size_t)l * GK + k] = f2bf(W[(size_t)l * GK + k] + acc[li]);
  }
}

// ---------------- K4: main GEMM  C[m][l] = sum_k A[m][k]*Mt[l][k] + bias[l] ----
// m97-style: 128x128 tile, BK=64, 4 waves (2x2), global_load_lds width 16,
// mfma_f32_16x16x32_bf16, single-buffered 2-barrier loop.
#define BM 128
#define BN 128
#define BK 64

__device__ __forceinline__ void async16(const bf16* g, bf16* l) {
  __builtin_amdgcn_global_load_lds((__attribute__((address_space(1))) void*)g,
                                   (__attribute__((address_space(3))) void*)l,
                                   16, 0, 0);
}

__global__ __launch_bounds__(256) void gemm_bf16(
    const bf16* __restrict__ A,    // [GM][GK] row-major
    const bf16* __restrict__ Bt,   // [GN][GK] row-major (B^T layout)
    const float* __restrict__ bias,// [GN]
    float* __restrict__ C)         // [GM][GN]
{
  __shared__ bf16 lA[BM * BK];   // 16 KB, row-major [128][64]
  __shared__ bf16 lB[BN * BK];   // 16 KB

  const int tid  = threadIdx.x;
  const int wave = tid >> 6, lane = tid & 63;
  const int bm = blockIdx.y * BM, bn = blockIdx.x * BN;
  const int wr = wave >> 1, wc = wave & 1;      // 2x2 waves -> 64x64 each

  // staging: thread t loads 8 bf16 (16B): row = t/8 (+32 per issue), col8 = t%8
  const int srow = tid >> 3;             // 0..31
  const int scol = (tid & 7) * 8;
  const bf16* gA = A  + (size_t)(bm + srow) * GK + scol;
  const bf16* gB = Bt + (size_t)(bn + srow) * GK + scol;

  f32x4 acc[4][4] = {};

  for (int k0 = 0; k0 < GK; k0 += BK) {
#pragma unroll
    for (int i = 0; i < 4; ++i) {
      // LDS dest is wave-uniform base; HW scatters lane*16B -> linear row-major
      async16(gA + (size_t)(i * 32) * GK + k0, &lA[(i * 32 + 8 * wave) * BK]);
      async16(gB + (size_t)(i * 32) * GK + k0, &lB[(i * 32 + 8 * wave) * BK]);
    }
    __syncthreads();   // compiler emits vmcnt(0) drain before barrier

#pragma unroll
    for (int ks = 0; ks < 2; ++ks) {
      bf16x8 af[4], bfr[4];
#pragma unroll
      for (int m = 0; m < 4; ++m)
        af[m] = *(const bf16x8*)&lA[(wr * 64 + m * 16 + (lane & 15)) * BK +
                                    ks * 32 + (lane >> 4) * 8];
#pragma unroll
      for (int n = 0; n < 4; ++n)
        bfr[n] = *(const bf16x8*)&lB[(wc * 64 + n * 16 + (lane & 15)) * BK +
                                     ks * 32 + (lane >> 4) * 8];
#pragma unroll
      for (int m = 0; m < 4; ++m)
#pragma unroll
        for (int n = 0; n < 4; ++n)
          acc[m][n] = __builtin_amdgcn_mfma_f32_16x16x32_bf16(
              af[m], bfr[n], acc[m][n], 0, 0, 0);
    }
    __syncthreads();
  }

  // epilogue: C/D layout col = lane&15, row = (lane>>4)*4 + i
  const int crow0 = bm + wr * 64;
  const int ccol0 = bn + wc * 64;
#pragma unroll
  for (int n = 0; n < 4; ++n) {
    const int col = ccol0 + n * 16 + (lane & 15);
    const float bv = bias[col];
#pragma unroll
    for (int m = 0; m < 4; ++m) {
#pragma unroll
      for (int i = 0; i < 4; ++i) {
        const int row = crow0 + m * 16 + (lane >> 4) * 4 + i;
        C[(size_t)row * GN + col] = acc[m][n][i] + bv;
      }
    }
  }
}

extern "C" void kernel_launch(void* const* d_in, const int* in_sizes, int n_in,
                              void* d_out, int out_size, void* d_ws, size_t ws_size,
                              hipStream_t stream)
{
  const float*     x    = (const float*)d_in[0];      // [4,2048,4096] f32
  const float*     c    = (const float*)d_in[1];      // [100] f32
  const long long* E    = (const long long*)d_in[2];  // [2,100] int64
  const float*     W    = (const float*)d_in[3];      // [4096,4096] f32 [out,in]
  const float*     bias = (const float*)d_in[4];      // [4096] f32
  float*           out  = (float*)d_out;              // [4,2048,4096] f32

  // workspace layout (bytes): Q 3.28MB | P 3.28MB | x_bf16 67.1MB | Mt 33.6MB
  char*  ws = (char*)d_ws;
  float* Q  = (float*)(ws);
  float* P  = (float*)(ws + 3276800);
  bf16*  xb = (bf16*) (ws + 6553600);
  bf16*  Mt = (bf16*) (ws + 6553600 + 67108864);

  build_tables<<<NFREQ, 256, 0, stream>>>(c, E, Q, P);
  cvt_f32_bf16<<<GM * GK / 8 / 256, 256, 0, stream>>>(x, xb);
  build_Mt<<<dim3(GK / 256, GN / LPER), 256, 0, stream>>>(W, P, Q, Mt);
  gemm_bf16<<<dim3(GN / BN, GM / BM), 256, 0, stream>>>(xb, Mt, bias, out);
}

// Round 2
// 661.856 us; speedup vs baseline: 1.3905x; 1.3905x over previous
//
#include <hip/hip_runtime.h>
#include <stdint.h>

// Problem constants
#define GM 8192      // rows of x (4*2048)
#define GN 4096      // output dim (D2)
#define GK 4096      // inner dim (D1)
#define NFREQ 100
#define ALPHA_F 300.0f

typedef __bf16 bf16;
typedef __attribute__((ext_vector_type(8))) __bf16 bf16x8;
typedef __attribute__((ext_vector_type(4))) float f32x4;

__device__ __forceinline__ bf16 f2bf(float f) {
  union { float f; uint32_t u; } v; v.f = f;
  uint32_t r = v.u + 0x7FFFu + ((v.u >> 16) & 1u);   // RNE
  uint16_t h = (uint16_t)(r >> 16);
  return __builtin_bit_cast(bf16, h);
}

// ---------------- K0: zero the P/Q tables (4 MB, incl. K-padding) ----------
__global__ __launch_bounds__(256) void zero_ws(uint4* __restrict__ p) {
  p[blockIdx.x * 256 + threadIdx.x] = uint4{0, 0, 0, 0};
}

// ---------------- K1: rank-200 factor tables, bf16, K padded to 256 --------
// Column layout (K dim): col 2j = cos term, col 2j+1 = sin term, cols 200..255 = 0.
// Pb [4096][256]: Pb[l][2j] = cos(2π l q_j/4096), Pb[l][2j+1] = -sin(...)
// Qbt[4096][256]: Qbt[k][2j] = s*c_j*cos(2π k r_j/4096), Qbt[k][2j+1] = s*c_j*sin(...)
// Then (Pb · Qbt^T)[l][k] = Delta_W[k][l]  (s = ALPHA/(D1*D2) folded into Q side)
__global__ __launch_bounds__(256) void build_tables(
    const float* __restrict__ c, const long long* __restrict__ E,
    bf16* __restrict__ Pb, bf16* __restrict__ Qbt)
{
  const int m  = blockIdx.x * 256 + threadIdx.x;  // 0..4095
  const int jc = blockIdx.y * 4;                  // 0,4,...,96
  const float w = 6.28318530717958647692f / 4096.0f;
  bf16x8 pv, qv;
#pragma unroll
  for (int t = 0; t < 4; ++t) {
    const int j = jc + t;
    const int r = (int)E[j];          // row freq (pairs with k)
    const int q = (int)E[NFREQ + j];  // col freq (pairs with l)
    const float cs = c[j] * (ALPHA_F / ((float)GK * (float)GN));
    float s1, c1, s2, c2;
    sincosf(w * (float)((m * r) & 4095), &s1, &c1);  // integer phase reduction
    qv[2 * t]     = f2bf(cs * c1);
    qv[2 * t + 1] = f2bf(cs * s1);
    sincosf(w * (float)((m * q) & 4095), &s2, &c2);
    pv[2 * t]     = f2bf(c2);
    pv[2 * t + 1] = f2bf(-s2);
  }
  *(bf16x8*)&Pb [m * 256 + 2 * jc] = pv;
  *(bf16x8*)&Qbt[m * 256 + 2 * jc] = qv;
}

// ---------------- K2: cast x (f32) -> bf16, 8 elems/thread ----------------
__global__ __launch_bounds__(256) void cvt_f32_bf16(
    const float* __restrict__ in, bf16* __restrict__ out)
{
  const int i = blockIdx.x * 256 + threadIdx.x;   // i < GM*GK/8
  float4 a = ((const float4*)in)[2 * i];
  float4 b = ((const float4*)in)[2 * i + 1];
  bf16x8 o;
  o[0] = f2bf(a.x); o[1] = f2bf(a.y); o[2] = f2bf(a.z); o[3] = f2bf(a.w);
  o[4] = f2bf(b.x); o[5] = f2bf(b.y); o[6] = f2bf(b.z); o[7] = f2bf(b.w);
  ((bf16x8*)out)[i] = o;
}

// ---------------- templated 128x128 MFMA GEMM, T2-swizzled LDS -------------
// C[m][n] = sum_k A[m][k] * Bt[n][k]  (+ epilogue)
//   EPI=0: out f32 = acc + aux[col]          (aux = bias)
//   EPI=1: out bf16 = f2bf(aux[row*GN+col] + acc)   (aux = W_base f32)
// LDS swizzle (rule #21: linear global_load_lds dest + inverse-swizzled global
// SOURCE + swizzled ds_read): 16B slot s of row holds global k-slot s^(row&7).
#define BM 128
#define BN 128
#define BK 64

__device__ __forceinline__ void async16(const bf16* g, bf16* l) {
  __builtin_amdgcn_global_load_lds((__attribute__((address_space(1))) void*)g,
                                   (__attribute__((address_space(3))) void*)l,
                                   16, 0, 0);
}

template<int KDIM, int EPI>
__global__ __launch_bounds__(256) void gemm_sw(
    const bf16* __restrict__ A,    // [M][KDIM] row-major
    const bf16* __restrict__ Bt,   // [N][KDIM] row-major (B^T layout)
    const float* __restrict__ aux, // bias [GN] (EPI=0) or W [M][GN] (EPI=1)
    void* __restrict__ outp,       // f32 [M][GN] or bf16 [M][GN]
    int nx)                        // blocks along N
{
  __shared__ bf16 lA[BM * BK];   // 16 KB
  __shared__ bf16 lB[BN * BK];   // 16 KB

  const int tid  = threadIdx.x;
  const int wave = tid >> 6, lane = tid & 63;

  // T1: bijective XCD swizzle (gridDim.x % 8 == 0 for both instantiations)
  const int nwg = gridDim.x;
  const int cpx = nwg >> 3;
  const int wg  = (blockIdx.x & 7) * cpx + (blockIdx.x >> 3);
  const int bx = wg % nx, by = wg / nx;
  const int bm = by * BM, bn = bx * BN;
  const int wr = wave >> 1, wc = wave & 1;      // 2x2 waves -> 64x64 each

  // staging: thread t -> LDS row srow (+i*32), dest slot t&7 (linear);
  // global source slot pre-swizzled so LDS slot s holds k-slot s^(row&7).
  const int srow  = tid >> 3;                   // 0..31
  const int sslot = (tid & 7) ^ (srow & 7);
  const bf16* gA = A  + (size_t)(bm + srow) * KDIM + sslot * 8;
  const bf16* gB = Bt + (size_t)(bn + srow) * KDIM + sslot * 8;

  f32x4 acc[4][4] = {};

  for (int k0 = 0; k0 < KDIM; k0 += BK) {
#pragma unroll
    for (int i = 0; i < 4; ++i) {
      async16(gA + (size_t)(i * 32) * KDIM + k0, &lA[(i * 32 + 8 * wave) * BK]);
      async16(gB + (size_t)(i * 32) * KDIM + k0, &lB[(i * 32 + 8 * wave) * BK]);
    }
    __syncthreads();

#pragma unroll
    for (int ks = 0; ks < 2; ++ks) {
      bf16x8 af[4], bfr[4];
#pragma unroll
      for (int m = 0; m < 4; ++m) {
        const int row  = wr * 64 + m * 16 + (lane & 15);
        const int slot = (ks * 4 + (lane >> 4)) ^ (row & 7);
        af[m] = *(const bf16x8*)&lA[row * BK + slot * 8];
      }
#pragma unroll
      for (int n = 0; n < 4; ++n) {
        const int row  = wc * 64 + n * 16 + (lane & 15);
        const int slot = (ks * 4 + (lane >> 4)) ^ (row & 7);
        bfr[n] = *(const bf16x8*)&lB[row * BK + slot * 8];
      }
#pragma unroll
      for (int m = 0; m < 4; ++m)
#pragma unroll
        for (int n = 0; n < 4; ++n)
          acc[m][n] = __builtin_amdgcn_mfma_f32_16x16x32_bf16(
              af[m], bfr[n], acc[m][n], 0, 0, 0);
    }
    __syncthreads();
  }

  // epilogue: C/D layout col = lane&15, row = (lane>>4)*4 + i
  const int crow0 = bm + wr * 64;
  const int ccol0 = bn + wc * 64;
#pragma unroll
  for (int n = 0; n < 4; ++n) {
    const int col = ccol0 + n * 16 + (lane & 15);
    float bv = 0.0f;
    if constexpr (EPI == 0) bv = aux[col];
#pragma unroll
    for (int m = 0; m < 4; ++m) {
#pragma unroll
      for (int i = 0; i < 4; ++i) {
        const int row = crow0 + m * 16 + (lane >> 4) * 4 + i;
        if constexpr (EPI == 0) {
          ((float*)outp)[(size_t)row * GN + col] = acc[m][n][i] + bv;
        } else {
          ((bf16*)outp)[(size_t)row * GN + col] =
              f2bf(aux[(size_t)row * GN + col] + acc[m][n][i]);
        }
      }
    }
  }
}

extern "C" void kernel_launch(void* const* d_in, const int* in_sizes, int n_in,
                              void* d_out, int out_size, void* d_ws, size_t ws_size,
                              hipStream_t stream)
{
  const float*     x    = (const float*)d_in[0];      // [4,2048,4096] f32
  const float*     c    = (const float*)d_in[1];      // [100] f32
  const long long* E    = (const long long*)d_in[2];  // [2,100] int64
  const float*     W    = (const float*)d_in[3];      // [4096,4096] f32 [out,in]
  const float*     bias = (const float*)d_in[4];      // [4096] f32
  float*           out  = (float*)d_out;              // [4,2048,4096] f32

  // workspace (bytes): xb 67.1MB | Mt 33.6MB | Pb 2MB | Qbt 2MB  (= 100 MB)
  char* ws = (char*)d_ws;
  bf16* xb  = (bf16*)(ws);
  bf16* Mt  = (bf16*)(ws + 67108864);
  bf16* Pb  = (bf16*)(ws + 100663296);
  bf16* Qbt = (bf16*)(ws + 102760448);

  // K0: zero Pb+Qbt (4 MB contiguous; covers the K=200..255 zero padding)
  zero_ws<<<1024, 256, 0, stream>>>((uint4*)Pb);
  // K1: spectral factor tables
  build_tables<<<dim3(16, 25), 256, 0, stream>>>(c, E, Pb, Qbt);
  // K2: x -> bf16
  cvt_f32_bf16<<<GM * GK / 8 / 256, 256, 0, stream>>>(x, xb);
  // K3: Mt[l][k] = bf16(W[l][k] + sum_j Pb[l][j]*Qbt[k][j])   (MFMA, K=256)
  gemm_sw<256, 1><<<1024, 256, 0, stream>>>(Pb, Qbt, W, (void*)Mt, 32);
  // K4: out[m][l] = sum_k xb[m][k]*Mt[l][k] + bias[l]          (MFMA, K=4096)
  gemm_sw<4096, 0><<<2048, 256, 0, stream>>>(xb, Mt, bias, (void*)out, 32);
}

// Round 5
// 522.451 us; speedup vs baseline: 1.7616x; 1.2668x over previous
//
#include <hip/hip_runtime.h>
#include <stdint.h>

// Problem constants
#define GM 8192      // rows of x (4*2048)
#define GN 4096      // output dim (D2)
#define GK 4096      // inner dim (D1)
#define NFREQ 100
#define ALPHA_F 300.0f

typedef __bf16 bf16;
typedef __attribute__((ext_vector_type(8))) __bf16 bf16x8;
typedef __attribute__((ext_vector_type(4))) float f32x4;

__device__ __forceinline__ bf16 f2bf(float f) {
  union { float f; uint32_t u; } v; v.f = f;
  uint32_t r = v.u + 0x7FFFu + ((v.u >> 16) & 1u);   // RNE
  uint16_t h = (uint16_t)(r >> 16);
  return __builtin_bit_cast(bf16, h);
}

__device__ __forceinline__ void async16(const bf16* g, bf16* l) {
  __builtin_amdgcn_global_load_lds((__attribute__((address_space(1))) void*)g,
                                   (__attribute__((address_space(3))) void*)l,
                                   16, 0, 0);
}

// ---------------- K0: zero the P/Q tables (4 MB, incl. K-padding) ----------
__global__ __launch_bounds__(256) void zero_ws(uint4* __restrict__ p) {
  p[blockIdx.x * 256 + threadIdx.x] = uint4{0, 0, 0, 0};
}

// ---------------- K1: rank-200 factor tables, bf16, K padded to 256 --------
__global__ __launch_bounds__(256) void build_tables(
    const float* __restrict__ c, const long long* __restrict__ E,
    bf16* __restrict__ Pb, bf16* __restrict__ Qbt)
{
  const int m  = blockIdx.x * 256 + threadIdx.x;  // 0..4095
  const int jc = blockIdx.y * 4;                  // 0,4,...,96
  const float w = 6.28318530717958647692f / 4096.0f;
  bf16x8 pv, qv;
#pragma unroll
  for (int t = 0; t < 4; ++t) {
    const int j = jc + t;
    const int r = (int)E[j];          // row freq (pairs with k)
    const int q = (int)E[NFREQ + j];  // col freq (pairs with l)
    const float cs = c[j] * (ALPHA_F / ((float)GK * (float)GN));
    float s1, c1, s2, c2;
    sincosf(w * (float)((m * r) & 4095), &s1, &c1);  // integer phase reduction
    qv[2 * t]     = f2bf(cs * c1);
    qv[2 * t + 1] = f2bf(cs * s1);
    sincosf(w * (float)((m * q) & 4095), &s2, &c2);
    pv[2 * t]     = f2bf(c2);
    pv[2 * t + 1] = f2bf(-s2);
  }
  *(bf16x8*)&Pb [m * 256 + 2 * jc] = pv;
  *(bf16x8*)&Qbt[m * 256 + 2 * jc] = qv;
}

// ---------------- K2: cast x (f32) -> bf16, 8 elems/thread ----------------
__global__ __launch_bounds__(256) void cvt_f32_bf16(
    const float* __restrict__ in, bf16* __restrict__ out)
{
  const int i = blockIdx.x * 256 + threadIdx.x;   // i < GM*GK/8
  float4 a = ((const float4*)in)[2 * i];
  float4 b = ((const float4*)in)[2 * i + 1];
  bf16x8 o;
  o[0] = f2bf(a.x); o[1] = f2bf(a.y); o[2] = f2bf(a.z); o[3] = f2bf(a.w);
  o[4] = f2bf(b.x); o[5] = f2bf(b.y); o[6] = f2bf(b.z); o[7] = f2bf(b.w);
  ((bf16x8*)out)[i] = o;
}

// ---------------- K3: 128x128 2-barrier GEMM (round-2 verified) ------------
// Mt[l][k] = bf16(W[l][k] + sum_j Pb[l][j]*Qbt[k][j]),  KDIM=256
#define BM 128
#define BN 128
#define BK 64

__global__ __launch_bounds__(256) void gemm_mt(
    const bf16* __restrict__ A, const bf16* __restrict__ Bt,
    const float* __restrict__ W, bf16* __restrict__ Mt)
{
  const int KDIM = 256;
  __shared__ bf16 lA[BM * BK];
  __shared__ bf16 lB[BN * BK];

  const int tid  = threadIdx.x;
  const int wave = tid >> 6, lane = tid & 63;
  const int nwg = gridDim.x, cpx = nwg >> 3;
  const int wg  = (blockIdx.x & 7) * cpx + (blockIdx.x >> 3);
  const int bx = wg & 31, by = wg >> 5;
  const int bm = by * BM, bn = bx * BN;
  const int wr = wave >> 1, wc = wave & 1;

  const int srow  = tid >> 3;
  const int sslot = (tid & 7) ^ (srow & 7);
  const bf16* gA = A  + (size_t)(bm + srow) * KDIM + sslot * 8;
  const bf16* gB = Bt + (size_t)(bn + srow) * KDIM + sslot * 8;

  f32x4 acc[4][4] = {};

  for (int k0 = 0; k0 < KDIM; k0 += BK) {
#pragma unroll
    for (int i = 0; i < 4; ++i) {
      async16(gA + (size_t)(i * 32) * KDIM + k0, &lA[(i * 32 + 8 * wave) * BK]);
      async16(gB + (size_t)(i * 32) * KDIM + k0, &lB[(i * 32 + 8 * wave) * BK]);
    }
    __syncthreads();
#pragma unroll
    for (int ks = 0; ks < 2; ++ks) {
      bf16x8 af[4], bfr[4];
#pragma unroll
      for (int m = 0; m < 4; ++m) {
        const int row  = wr * 64 + m * 16 + (lane & 15);
        const int slot = (ks * 4 + (lane >> 4)) ^ (row & 7);
        af[m] = *(const bf16x8*)&lA[row * BK + slot * 8];
      }
#pragma unroll
      for (int n = 0; n < 4; ++n) {
        const int row  = wc * 64 + n * 16 + (lane & 15);
        const int slot = (ks * 4 + (lane >> 4)) ^ (row & 7);
        bfr[n] = *(const bf16x8*)&lB[row * BK + slot * 8];
      }
#pragma unroll
      for (int m = 0; m < 4; ++m)
#pragma unroll
        for (int n = 0; n < 4; ++n)
          acc[m][n] = __builtin_amdgcn_mfma_f32_16x16x32_bf16(
              af[m], bfr[n], acc[m][n], 0, 0, 0);
    }
    __syncthreads();
  }

  const int crow0 = bm + wr * 64;
  const int ccol0 = bn + wc * 64;
#pragma unroll
  for (int n = 0; n < 4; ++n) {
    const int col = ccol0 + n * 16 + (lane & 15);
#pragma unroll
    for (int m = 0; m < 4; ++m) {
#pragma unroll
      for (int i = 0; i < 4; ++i) {
        const int row = crow0 + m * 16 + (lane >> 4) * 4 + i;
        Mt[(size_t)row * GN + col] = f2bf(W[(size_t)row * GN + col] + acc[m][n][i]);
      }
    }
  }
}

// ---------------- K4: 256x256 8-phase GEMM (T1+T2+T3+T4+T5) ----------------
// 8 phases / 2 K-tiles per iteration. Each phase reads EXACTLY one 128-row
// half per operand; each region is staged exactly one phase after its last
// reader; vmcnt(6) only at phases 4 and 8 (3 half-tiles in flight).
//   region last-reader (buf0): A0:ph1  B1:ph2  A1:ph3  B0:ph4   (+4 for buf1)
//   stages: ph1:buf1.B0(2t+1)  ph2:A0 ph3:B1 ph4:A1 ph5:B0 (buf0, 2t+2)
//           ph6:A0 ph7:B1 ph8:A1 (buf1, 2t+3)
#define TBM 256
#define TBN 256
#define TBK 64
#define NITER (GK / TBK / 2)   // 32 iterations, 2 K-tiles each
#define BUFE (256 * 64)        // bf16 elems per operand per buffer

__device__ __forceinline__ void hard_barrier() {
  __builtin_amdgcn_sched_barrier(0);
  asm volatile("" ::: "memory");
  __builtin_amdgcn_s_barrier();
  asm volatile("" ::: "memory");
  __builtin_amdgcn_sched_barrier(0);
}

__global__ __launch_bounds__(512, 2) void gemm8(
    const bf16* __restrict__ A,    // [GM][GK]
    const bf16* __restrict__ Bt,   // [GN][GK]
    const float* __restrict__ bias,
    float* __restrict__ C)         // [GM][GN]
{
  __shared__ bf16 lds[4 * BUFE];   // 128 KiB: [buf][A|B][256 rows][64 k]

  const int tid  = threadIdx.x;
  const int wave = tid >> 6, lane = tid & 63;
  const int wr = wave >> 2, wc = wave & 3;          // 2(M) x 4(N) waves

  // T1: bijective XCD swizzle (nwg = 512)
  const int wg = (blockIdx.x & 7) * 64 + (blockIdx.x >> 3);
  const int bx = wg & 15, by = wg >> 4;             // 16 x 32 grid
  const int bm = by * TBM, bn = bx * TBN;

  // staging: lane -> row (lane>>3), dest slot (lane&7) linear; global source
  // slot pre-swizzled so LDS slot s of row r holds global k-slot s^(r&7).
  const int sslot = (lane & 7) ^ ((lane >> 3) & 7);
  const bf16* pA = A  + (size_t)(bm + wave * 16 + (lane >> 3)) * GK + sslot * 8;
  const bf16* pB = Bt + (size_t)(bn + wave * 16 + (lane >> 3)) * GK + sslot * 8;

// stage one 128-row half-tile of one operand: 2 x global_load_lds per thread
#define STAGE(ptr, buf, op, h, tt)                                              \
  {                                                                             \
    const bf16* g_ = (ptr) + (size_t)((h) * 128) * GK + (size_t)(tt) * TBK;     \
    bf16* d_ = &lds[(buf) * 2 * BUFE + (op) * BUFE + ((h) * 128 + wave * 16) * 64]; \
    async16(g_, d_);                                                            \
    async16(g_ + (size_t)8 * GK, d_ + 8 * 64);                                  \
  }

// LDA(mh): A rows mh*128 + wr*64 + q*16 + (lane&15)  -- one half only
#define LDA(cb, mh)                                                             \
  _Pragma("unroll") for (int q = 0; q < 4; ++q)                                 \
  _Pragma("unroll") for (int ks = 0; ks < 2; ++ks) {                            \
    const int row_ = (mh) * 128 + wr * 64 + q * 16 + (lane & 15);               \
    const int sl_  = (ks * 4 + (lane >> 4)) ^ (row_ & 7);                       \
    af[q][ks] = *(const bf16x8*)&lds[(cb) + row_ * 64 + sl_ * 8];               \
  }

// LDB(nh): Bt rows nh*128 + wc*32 + r*16 + (lane&15) -- one half only
#define LDB(cb, nh)                                                             \
  _Pragma("unroll") for (int r = 0; r < 2; ++r)                                 \
  _Pragma("unroll") for (int ks = 0; ks < 2; ++ks) {                            \
    const int row_ = (nh) * 128 + wc * 32 + r * 16 + (lane & 15);               \
    const int sl_  = (ks * 4 + (lane >> 4)) ^ (row_ & 7);                       \
    bfr[r][ks] = *(const bf16x8*)&lds[(cb) + BUFE + row_ * 64 + sl_ * 8];       \
  }

#define MM(mh, nh)                                                              \
  _Pragma("unroll") for (int ks = 0; ks < 2; ++ks)                              \
  _Pragma("unroll") for (int q = 0; q < 4; ++q)                                 \
  _Pragma("unroll") for (int r = 0; r < 2; ++r)                                 \
    acc[(mh) * 4 + q][(nh) * 2 + r] = __builtin_amdgcn_mfma_f32_16x16x32_bf16(  \
        af[q][ks], bfr[r][ks], acc[(mh) * 4 + q][(nh) * 2 + r], 0, 0, 0);

#define WAIT_LGKM0()                                        \
  asm volatile("s_waitcnt lgkmcnt(0)" ::: "memory");        \
  __builtin_amdgcn_sched_barrier(0);

#define MFMA_BLOCK(mh, nh)                                  \
  WAIT_LGKM0();                                             \
  __builtin_amdgcn_s_setprio(1);                            \
  MM(mh, nh);                                               \
  __builtin_amdgcn_s_setprio(0);

  // prologue: tile0 {A0,B1,A1,B0}; vmcnt(4); tile1 {A0,B1,A1}; vmcnt(6)
  STAGE(pA, 0, 0, 0, 0); STAGE(pB, 0, 1, 1, 0);
  STAGE(pA, 0, 0, 1, 0); STAGE(pB, 0, 1, 0, 0);
  asm volatile("s_waitcnt vmcnt(4)" ::: "memory");
  STAGE(pA, 1, 0, 0, 1); STAGE(pB, 1, 1, 1, 1); STAGE(pA, 1, 0, 1, 1);
  asm volatile("s_waitcnt vmcnt(6)" ::: "memory");
  hard_barrier();

  f32x4 acc[8][4] = {};
  bf16x8 af[4][2], bfr[2][2];

  for (int t = 0; t < NITER; ++t) {
    const bool pf = (t + 1 < NITER);     // stage tiles 2t+2 / 2t+3 ?
    const int t2 = 2 * t + 2, t3 = 2 * t + 3;
    // ================= K-tile 2t from buf0 =================
    // ph1: (0,0); stage buf1.B0 <- tile 2t+1 (last read ph8 prev iter)
    LDA(0, 0); LDB(0, 0);
    STAGE(pB, 1, 1, 0, 2 * t + 1);
    asm volatile("s_waitcnt lgkmcnt(8)" ::: "memory");
    hard_barrier();
    MFMA_BLOCK(0, 0);
    hard_barrier();
    // ph2: (0,1); stage buf0.A0 <- tile 2t+2 (A0 last read ph1)
    LDB(0, 1);
    if (pf) STAGE(pA, 0, 0, 0, t2);
    hard_barrier();
    MFMA_BLOCK(0, 1);
    hard_barrier();
    // ph3: (1,1); stage buf0.B1 (last read ph2)
    LDA(0, 1);
    if (pf) STAGE(pB, 0, 1, 1, t2);
    hard_barrier();
    MFMA_BLOCK(1, 1);
    hard_barrier();
    // ph4: (1,0); stage buf0.A1 (last read ph3); GATE: vmcnt
    LDB(0, 0);
    if (pf) STAGE(pA, 0, 0, 1, t2);
    hard_barrier();
    MFMA_BLOCK(1, 0);
    if (pf) { asm volatile("s_waitcnt vmcnt(6)" ::: "memory"); }
    else    { asm volatile("s_waitcnt vmcnt(0)" ::: "memory"); }
    hard_barrier();
    // ================= K-tile 2t+1 from buf1 =================
    const int cb1 = 2 * BUFE;
    // ph5: (0,0); stage buf0.B0 <- tile 2t+2 (B0 last read ph4)
    LDA(cb1, 0); LDB(cb1, 0);
    if (pf) STAGE(pB, 0, 1, 0, t2);
    asm volatile("s_waitcnt lgkmcnt(8)" ::: "memory");
    hard_barrier();
    MFMA_BLOCK(0, 0);
    hard_barrier();
    // ph6: (0,1); stage buf1.A0 <- tile 2t+3 (A0 last read ph5)
    LDB(cb1, 1);
    if (pf) STAGE(pA, 1, 0, 0, t3);
    hard_barrier();
    MFMA_BLOCK(0, 1);
    hard_barrier();
    // ph7: (1,1); stage buf1.B1 (last read ph6)
    LDA(cb1, 1);
    if (pf) STAGE(pB, 1, 1, 1, t3);
    hard_barrier();
    MFMA_BLOCK(1, 1);
    hard_barrier();
    // ph8: (1,0); stage buf1.A1 (last read ph7); GATE: vmcnt
    LDB(cb1, 0);
    if (pf) STAGE(pA, 1, 0, 1, t3);
    hard_barrier();
    MFMA_BLOCK(1, 0);
    if (pf) { asm volatile("s_waitcnt vmcnt(6)" ::: "memory"); }
    else    { asm volatile("s_waitcnt vmcnt(0)" ::: "memory"); }
    hard_barrier();
  }

  // epilogue: within each 16x16 frag, col = lane&15, row = (lane>>4)*4 + i
#pragma unroll
  for (int nh = 0; nh < 2; ++nh)
#pragma unroll
  for (int r = 0; r < 2; ++r) {
    const int col = bn + nh * 128 + wc * 32 + r * 16 + (lane & 15);
    const float bv = bias[col];
#pragma unroll
    for (int mh = 0; mh < 2; ++mh)
#pragma unroll
    for (int q = 0; q < 4; ++q) {
#pragma unroll
      for (int i = 0; i < 4; ++i) {
        const int row = bm + mh * 128 + wr * 64 + q * 16 + (lane >> 4) * 4 + i;
        C[(size_t)row * GN + col] = acc[mh * 4 + q][nh * 2 + r][i] + bv;
      }
    }
  }
#undef STAGE
#undef LDA
#undef LDB
#undef MM
#undef WAIT_LGKM0
#undef MFMA_BLOCK
}

extern "C" void kernel_launch(void* const* d_in, const int* in_sizes, int n_in,
                              void* d_out, int out_size, void* d_ws, size_t ws_size,
                              hipStream_t stream)
{
  const float*     x    = (const float*)d_in[0];      // [4,2048,4096] f32
  const float*     c    = (const float*)d_in[1];      // [100] f32
  const long long* E    = (const long long*)d_in[2];  // [2,100] int64
  const float*     W    = (const float*)d_in[3];      // [4096,4096] f32 [out,in]
  const float*     bias = (const float*)d_in[4];      // [4096] f32
  float*           out  = (float*)d_out;              // [4,2048,4096] f32

  // workspace (bytes): xb 67.1MB | Mt 33.6MB | Pb 2MB | Qbt 2MB  (= 100 MB)
  char* ws = (char*)d_ws;
  bf16* xb  = (bf16*)(ws);
  bf16* Mt  = (bf16*)(ws + 67108864);
  bf16* Pb  = (bf16*)(ws + 100663296);
  bf16* Qbt = (bf16*)(ws + 102760448);

  zero_ws<<<1024, 256, 0, stream>>>((uint4*)Pb);
  build_tables<<<dim3(16, 25), 256, 0, stream>>>(c, E, Pb, Qbt);
  cvt_f32_bf16<<<GM * GK / 8 / 256, 256, 0, stream>>>(x, xb);
  gemm_mt<<<1024, 256, 0, stream>>>(Pb, Qbt, W, Mt);
  gemm8<<<dim3(512), 512, 0, stream>>>(xb, Mt, bias, out);
}